// Round 12
// baseline (780.152 us; speedup 1.0000x reference)
//
#include <hip/hip_runtime.h>
#include <hip/hip_bf16.h>
#include <hip/hip_fp16.h>

#define N_NODES 500000
#define N_EDGES 8000000
#define HID 128
#define NPB 64       // nodes per block in fallback MLP kernel
#define LDP 132      // padded LDS row (floats) for fallback

#define BSH 9        // 512 nodes per bucket
#define BNODES 512
#define NBUCK 977    // ceil(500000/512)
#define CAPB 9216    // slots per bucket region
#define EPB 16384    // edges per binning block
#define DSTMASK 0x7FFFFu

#define MNPB 256     // nodes per block in MFMA MLP (8 waves x 32 rows)
#define HPAD 136     // padded H row in bf16 elems (272B, 16B-aligned rows)

typedef __attribute__((ext_vector_type(8))) short bf16x8;
typedef __attribute__((ext_vector_type(4))) float f32x4;

__device__ __forceinline__ ushort f2bf(float f) {
    unsigned u = __float_as_uint(f);
    return (ushort)((u + 0x7fffu + ((u >> 16) & 1u)) >> 16);   // RNE
}
__device__ __forceinline__ float bf2f(ushort h) {
    return __uint_as_float((unsigned)h << 16);
}
// pack 2 f32 -> 2 bf16 in one u32 (lo->bits[15:0], hi->bits[31:16])
__device__ __forceinline__ unsigned cvt_pk_bf16(float lo, float hi) {
    unsigned r;
    asm("v_cvt_pk_bf16_f32 %0, %1, %2" : "=v"(r) : "v"(lo), "v"(hi));
    return r;
}

// ---------------------------------------------------------------------------
// Fast-path workspace layout (bytes), needs 80,168,192:
//   [0, 4,096)                 gcnt      int[NBUCK]         (zeroed)
//   [4,096, 4,608)             colsum    float[128]         (zeroed)
//   [4,608, 2,004,608)         deg_extra float[N_NODES]     (zeroed)
//   [2,004,608, 18,004,608)    agg_extra float[N_NODES*8]   (zeroed)
//   [18,004,608, 54,020,736)   region    u32[NBUCK*CAPB]
//   [54,020,736, 70,020,736)   agg       float[N_NODES*8]
//   [70,020,736, 72,020,736)   degf      float[N_NODES]
//   [72,020,736, 80,020,736)   xh        half[N_NODES*8]
//   [80,020,736, 80,037,120)   P1 packed W1 bf16 hi/lo frags
//   [80,037,120, 80,102,656)   P2 packed W2
//   [80,102,656, 80,168,192)   P3 packed W3
// ---------------------------------------------------------------------------

// ---- x -> fp16 shadow copy (16 B per node) --------------------------------
__global__ __launch_bounds__(256) void k_xhalf(
    const float4* __restrict__ x4, uint4* __restrict__ xh)
{
    int n = blockIdx.x * 256 + threadIdx.x;
    if (n >= N_NODES) return;
    float4 a = x4[(size_t)2 * n], b = x4[(size_t)2 * n + 1];
    __half2 p0 = __floats2half2_rn(a.x, a.y);
    __half2 p1 = __floats2half2_rn(a.z, a.w);
    __half2 p2 = __floats2half2_rn(b.x, b.y);
    __half2 p3 = __floats2half2_rn(b.z, b.w);
    uint4 o;
    o.x = *(unsigned*)&p0; o.y = *(unsigned*)&p1;
    o.z = *(unsigned*)&p2; o.w = *(unsigned*)&p3;
    xh[n] = o;
}

// ---- phase 1: bin edges by src bucket -------------------------------------
__global__ __launch_bounds__(256) void k_bin(
    const int* __restrict__ ei, const float4* __restrict__ x4,
    int* __restrict__ gcnt, unsigned* __restrict__ region,
    float* __restrict__ agg_extra, float* __restrict__ deg_extra)
{
    __shared__ int cntA[NBUCK];
    __shared__ int baseB[NBUCK];
    int tid = threadIdx.x;
    for (int b = tid; b < NBUCK; b += 256) cntA[b] = 0;
    __syncthreads();
    int e0 = blockIdx.x * EPB;

    // pass A: per-block bucket histogram (vectorized int4 reads)
    #pragma unroll 4
    for (int k = 0; k < EPB / 1024; ++k) {
        int e = e0 + k * 1024 + tid * 4;
        if (e + 3 < N_EDGES) {
            int4 s4 = *(const int4*)(ei + e);
            atomicAdd(&cntA[s4.x >> BSH], 1);
            atomicAdd(&cntA[s4.y >> BSH], 1);
            atomicAdd(&cntA[s4.z >> BSH], 1);
            atomicAdd(&cntA[s4.w >> BSH], 1);
        } else {
            for (int j = 0; j < 4; ++j)
                if (e + j < N_EDGES) atomicAdd(&cntA[ei[e + j] >> BSH], 1);
        }
    }
    __syncthreads();

    // reserve global ranges: one global atomic per (block, bucket)
    for (int b = tid; b < NBUCK; b += 256) {
        int c = cntA[b];
        baseB[b] = (c > 0) ? atomicAdd(&gcnt[b], c) : 0;
        cntA[b] = 0;
    }
    __syncthreads();

    // pass B: place edges
    #pragma unroll 2
    for (int k = 0; k < EPB / 1024; ++k) {
        int e = e0 + k * 1024 + tid * 4;
        if (e + 3 < N_EDGES) {
            int4 s4 = *(const int4*)(ei + e);
            int4 d4 = *(const int4*)(ei + N_EDGES + e);
            int ss[4] = {s4.x, s4.y, s4.z, s4.w};
            int dd[4] = {d4.x, d4.y, d4.z, d4.w};
            #pragma unroll
            for (int j = 0; j < 4; ++j) {
                int s = ss[j], d = dd[j];
                int b = s >> BSH;
                int pos = atomicAdd(&cntA[b], 1);
                int slot = baseB[b] + pos;
                if (slot < CAPB) {
                    region[(size_t)b * CAPB + slot] =
                        ((unsigned)(s & (BNODES - 1)) << 19) | (unsigned)d;
                } else {
                    float4 a = x4[(size_t)2 * d];
                    float4 bb = x4[(size_t)2 * d + 1];
                    float* p = agg_extra + (size_t)s * 8;
                    atomicAdd(p + 0, a.x); atomicAdd(p + 1, a.y);
                    atomicAdd(p + 2, a.z); atomicAdd(p + 3, a.w);
                    atomicAdd(p + 4, bb.x); atomicAdd(p + 5, bb.y);
                    atomicAdd(p + 6, bb.z); atomicAdd(p + 7, bb.w);
                    atomicAdd(deg_extra + s, 1.0f);
                }
            }
        } else {
            for (int j = 0; j < 4; ++j) {
                if (e + j >= N_EDGES) break;
                int s = ei[e + j], d = ei[N_EDGES + e + j];
                int b = s >> BSH;
                int pos = atomicAdd(&cntA[b], 1);
                int slot = baseB[b] + pos;
                if (slot < CAPB) {
                    region[(size_t)b * CAPB + slot] =
                        ((unsigned)(s & (BNODES - 1)) << 19) | (unsigned)d;
                } else {
                    float4 a = x4[(size_t)2 * d];
                    float4 bb = x4[(size_t)2 * d + 1];
                    float* p = agg_extra + (size_t)s * 8;
                    atomicAdd(p + 0, a.x); atomicAdd(p + 1, a.y);
                    atomicAdd(p + 2, a.z); atomicAdd(p + 3, a.w);
                    atomicAdd(p + 4, bb.x); atomicAdd(p + 5, bb.y);
                    atomicAdd(p + 6, bb.z); atomicAdd(p + 7, bb.w);
                    atomicAdd(deg_extra + s, 1.0f);
                }
            }
        }
    }
}

// ---- phase 2: per-bucket counting sort + register accumulate --------------
__device__ __forceinline__ void addx(float* s, uint4 v) {
    const __half2* h = (const __half2*)&v;
    #pragma unroll
    for (int c = 0; c < 4; ++c) {
        float2 f = __half22float2(h[c]);
        s[2 * c]     += f.x;
        s[2 * c + 1] += f.y;
    }
}

__global__ __launch_bounds__(512) void k_gather(
    const unsigned* __restrict__ region, const int* __restrict__ gcnt,
    const uint4* __restrict__ xh,
    const float4* __restrict__ agg_extra4, const float* __restrict__ deg_extra,
    float4* __restrict__ agg4, float* __restrict__ degf)
{
    __shared__ unsigned sorted[CAPB];    // 36.9 KB
    __shared__ int cnt[BNODES];          // histogram (preserved)
    __shared__ int scan[BNODES];         // inclusive scan
    __shared__ int run[BNODES];          // scatter cursors
    int tid = threadIdx.x;
    int b = blockIdx.x;

    cnt[tid] = 0;
    run[tid] = 0;
    __syncthreads();

    int ne = gcnt[b];
    if (ne > CAPB) ne = CAPB;
    const unsigned* reg = region + (size_t)b * CAPB;

    // pass 1: histogram of local src (1 LDS atomic/edge)
    for (int i = tid; i < ne; i += 512)
        atomicAdd(&cnt[reg[i] >> 19], 1);
    __syncthreads();

    // inclusive Hillis-Steele scan over 512 counts
    scan[tid] = cnt[tid];
    __syncthreads();
    #pragma unroll
    for (int s = 1; s < BNODES; s <<= 1) {
        int v = (tid >= s) ? scan[tid - s] : 0;
        __syncthreads();
        scan[tid] += v;
        __syncthreads();
    }

    // pass 2: scatter dst ids to per-node contiguous runs (1 LDS atomic/edge)
    for (int i = tid; i < ne; i += 512) {
        unsigned p = reg[i];
        int ls = (int)(p >> 19);
        int pos = atomicAdd(&run[ls], 1);
        sorted[(scan[ls] - cnt[ls]) + pos] = p & DSTMASK;
    }
    __syncthreads();

    // pass 3: one thread per node, register accumulation (no atomics),
    // 8 independent gathers in flight
    int deg  = cnt[tid];
    int base = scan[tid] - cnt[tid];
    float s[8];
    #pragma unroll
    for (int c = 0; c < 8; ++c) s[c] = 0.0f;

    int j = 0;
    for (; j + 8 <= deg; j += 8) {
        uint4 xv[8];
        #pragma unroll
        for (int q = 0; q < 8; ++q) xv[q] = xh[sorted[base + j + q]];
        #pragma unroll
        for (int q = 0; q < 8; ++q) addx(s, xv[q]);
    }
    for (; j + 4 <= deg; j += 4) {
        uint4 x0 = xh[sorted[base + j]];
        uint4 x1 = xh[sorted[base + j + 1]];
        uint4 x2 = xh[sorted[base + j + 2]];
        uint4 x3 = xh[sorted[base + j + 3]];
        addx(s, x0); addx(s, x1); addx(s, x2); addx(s, x3);
    }
    for (; j < deg; ++j) {
        uint4 xv = xh[sorted[base + j]];
        addx(s, xv);
    }

    int gn = b * BNODES + tid;
    if (gn < N_NODES) {
        float4 e0 = agg_extra4[(size_t)2 * gn];
        float4 e1 = agg_extra4[(size_t)2 * gn + 1];
        agg4[(size_t)2 * gn] = make_float4(
            s[0] + e0.x, s[1] + e0.y, s[2] + e0.z, s[3] + e0.w);
        agg4[(size_t)2 * gn + 1] = make_float4(
            s[4] + e1.x, s[5] + e1.y, s[6] + e1.z, s[7] + e1.w);
        degf[gn] = (float)deg + deg_extra[gn];
    }
}

// ---- pack W into MFMA B-fragment order, split bf16 hi/lo ------------------
// Layout: P[(ks*8+ct)*2 + hl][lane 0..63][j 0..7]  (ushort)
__global__ __launch_bounds__(256) void k_pack(
    const float* __restrict__ W1, const float* __restrict__ W2,
    const float* __restrict__ W3,
    ushort* __restrict__ P1, ushort* __restrict__ P2, ushort* __restrict__ P3)
{
    int b = blockIdx.x;
    const float* W = (b == 0) ? W1 : ((b == 1) ? W2 : W3);
    ushort* P = (b == 0) ? P1 : ((b == 1) ? P2 : P3);
    int KS = (b == 0) ? 1 : 4;
    int total = KS * 8 * 64 * 8;
    for (int i = threadIdx.x; i < total; i += 256) {
        int j    = i & 7;
        int lane = (i >> 3) & 63;
        int ct   = (i >> 9) & 7;
        int ks   = i >> 12;
        int k = ks * 32 + (lane >> 4) * 8 + j;
        int c = ct * 16 + (lane & 15);
        float wv = 0.0f;
        if (b == 0) { if (k < 8) wv = W[k * HID + c]; }
        else        { wv = W[k * HID + c]; }
        ushort hi = f2bf(wv);
        float  lo = wv - bf2f(hi);
        P[(((ks * 8 + ct) * 2 + 0) * 64 + lane) * 8 + j] = hi;
        P[(((ks * 8 + ct) * 2 + 1) * 64 + lane) * 8 + j] = f2bf(lo);
    }
}

// ---- one MFMA layer, 32 rows/wave, FORCED 8-deep pipelined B loads --------
// Quad q: ks=q>>2, grp=(q>>1)&1, hl=q&1, frags f=0..3 -> ct=grp*4+f.
// sched_barrier(0) after each prefetch pins the issue order so the compiler
// cannot collapse the pipeline (r11: it rematerialized loads next to use,
// VGPR stayed 64). Here B[8][4] = 128 VGPR must stay live.
template<int KS, bool STORE>
__device__ __forceinline__ void mfma_layer(
    ushort (&H)[MNPB][HPAD],
    const ushort* __restrict__ P, const float* __restrict__ bias,
    int rbase, int l, float* csum, int nbase)
{
    const int cl = l & 15;
    const int g  = l >> 4;
    constexpr int NQ = KS * 4;
    constexpr int DEPTH = (NQ < 8) ? NQ : 8;

    f32x4 acc[8][2];
    #pragma unroll
    for (int ct = 0; ct < 8; ++ct) {
        float bv = bias[ct * 16 + cl];
        f32x4 b4 = {bv, bv, bv, bv};
        acc[ct][0] = b4;
        acc[ct][1] = b4;
    }

    // all A fragments up front (LDS; one lgkm region)
    bf16x8 A0[KS], A1[KS];
    #pragma unroll
    for (int ks = 0; ks < KS; ++ks) {
        int col = ks * 32 + g * 8;
        A0[ks] = *(const bf16x8*)&H[rbase + cl][col];
        A1[ks] = *(const bf16x8*)&H[rbase + 16 + cl][col];
    }

    bf16x8 B[DEPTH][4];     // DEPTH-quad rolling buffer
    #pragma unroll
    for (int q = 0; q < DEPTH; ++q) {
        #pragma unroll
        for (int f = 0; f < 4; ++f)
            B[q][f] = *(const bf16x8*)(P +
                (size_t)(((q >> 2) * 8 + ((q >> 1) & 1) * 4 + f) * 1024
                         + (q & 1) * 512 + l * 8));
    }
    __builtin_amdgcn_sched_barrier(0);

    #pragma unroll
    for (int q = 0; q < NQ; ++q) {
        const int ks  = q >> 2;
        const int grp = (q >> 1) & 1;
        const int buf = q % DEPTH;
        #pragma unroll
        for (int f = 0; f < 4; ++f) {
            const int ct = grp * 4 + f;
            acc[ct][0] = __builtin_amdgcn_mfma_f32_16x16x32_bf16(A0[ks], B[buf][f], acc[ct][0], 0, 0, 0);
            acc[ct][1] = __builtin_amdgcn_mfma_f32_16x16x32_bf16(A1[ks], B[buf][f], acc[ct][1], 0, 0, 0);
        }
        if (q + DEPTH < NQ) {
            const int qn = q + DEPTH;
            #pragma unroll
            for (int f = 0; f < 4; ++f)
                B[buf][f] = *(const bf16x8*)(P +
                    (size_t)(((qn >> 2) * 8 + ((qn >> 1) & 1) * 4 + f) * 1024
                             + (qn & 1) * 512 + l * 8));
        }
        __builtin_amdgcn_sched_barrier(0);
    }

    if (STORE) {
        #pragma unroll
        for (int ct = 0; ct < 8; ++ct) {
            #pragma unroll
            for (int rt = 0; rt < 2; ++rt) {
                f32x4 a = acc[ct][rt];
                unsigned p0 = cvt_pk_bf16(fmaxf(a[0], 0.f), fmaxf(a[1], 0.f));
                unsigned p1 = cvt_pk_bf16(fmaxf(a[2], 0.f), fmaxf(a[3], 0.f));
                int r0 = rbase + rt * 16 + g * 4;
                int c  = ct * 16 + cl;
                H[r0 + 0][c] = (ushort)p0;
                H[r0 + 1][c] = (ushort)(p0 >> 16);
                H[r0 + 2][c] = (ushort)p1;
                H[r0 + 3][c] = (ushort)(p1 >> 16);
            }
        }
    } else {
        #pragma unroll
        for (int ct = 0; ct < 8; ++ct) {
            float part = 0.0f;
            #pragma unroll
            for (int rt = 0; rt < 2; ++rt) {
                f32x4 a = acc[ct][rt];
                #pragma unroll
                for (int j = 0; j < 4; ++j) {
                    int gn = nbase + rbase + rt * 16 + g * 4 + j;
                    float h = fmaxf(a[j], 0.0f);
                    part += (gn < N_NODES) ? h : 0.0f;
                }
            }
            part += __shfl_xor(part, 16, 64);
            part += __shfl_xor(part, 32, 64);
            if (g == 0) atomicAdd(&csum[ct * 16 + cl], part);
        }
    }
}

// ---- fused 3-layer MLP: 8 waves x 32 rows, forced-pipeline B loads --------
__global__ __launch_bounds__(512, 4) void k_mlp_mfma(
    const float4* __restrict__ x4, const float4* __restrict__ agg4,
    const float* __restrict__ degf,
    const ushort* __restrict__ P1, const float* __restrict__ b1,
    const ushort* __restrict__ P2, const float* __restrict__ b2,
    const ushort* __restrict__ P3, const float* __restrict__ b3,
    float* __restrict__ colsum)
{
    __shared__ ushort H[MNPB][HPAD];    // 69.6 KB -> 2 blocks/CU (16 waves)
    __shared__ float csum[HID];

    const int tid = threadIdx.x;        // 0..511
    const int wv  = tid >> 6;           // 0..7
    const int l   = tid & 63;
    const int rbase = wv * 32;          // wave owns rows [rbase, rbase+32)
    const int nbase = blockIdx.x * MNPB;

    if (tid < HID) csum[tid] = 0.0f;
    __syncthreads();

    if (l < 32) {
        int rr = l;
        int gn = nbase + rbase + rr;
        float vv[8];
        if (gn < N_NODES) {
            float4 xa = x4[(size_t)2 * gn], xb = x4[(size_t)2 * gn + 1];
            float4 a0 = agg4[(size_t)2 * gn];
            float4 a1 = agg4[(size_t)2 * gn + 1];
            float rd = 1.0f / fmaxf(degf[gn], 1.0f);
            vv[0] = xa.x + a0.x * rd; vv[1] = xa.y + a0.y * rd;
            vv[2] = xa.z + a0.z * rd; vv[3] = xa.w + a0.w * rd;
            vv[4] = xb.x + a1.x * rd; vv[5] = xb.y + a1.y * rd;
            vv[6] = xb.z + a1.z * rd; vv[7] = xb.w + a1.w * rd;
        } else {
            #pragma unroll
            for (int j = 0; j < 8; ++j) vv[j] = 0.0f;
        }
        uint4 hv;
        hv.x = cvt_pk_bf16(vv[0], vv[1]);
        hv.y = cvt_pk_bf16(vv[2], vv[3]);
        hv.z = cvt_pk_bf16(vv[4], vv[5]);
        hv.w = cvt_pk_bf16(vv[6], vv[7]);
        int row = rbase + rr;
        uint4 z = {0, 0, 0, 0};
        *(uint4*)&H[row][0]  = hv;
        *(uint4*)&H[row][8]  = z;
        *(uint4*)&H[row][16] = z;
        *(uint4*)&H[row][24] = z;
    }
    // no barrier: all layer dataflow is wave-local (wave reads/writes only
    // its own 32 rows; per-wave LDS ops execute in order)

    mfma_layer<1, true >(H, P1, b1, rbase, l, csum, nbase);  // 8 -> 128
    mfma_layer<4, true >(H, P2, b2, rbase, l, csum, nbase);  // 128 -> 128
    mfma_layer<4, false>(H, P3, b3, rbase, l, csum, nbase);  // 128 -> 128 + reduce

    __syncthreads();
    if (tid < HID) atomicAdd(&colsum[tid], csum[tid]);
}

// ---- fallback path kernels (ws too small) ---------------------------------
__global__ __launch_bounds__(256) void k_scatter(
    const int* __restrict__ ei, const float4* __restrict__ x4,
    float* __restrict__ agg, float* __restrict__ deg)
{
    int e = blockIdx.x * 256 + threadIdx.x;
    if (e >= N_EDGES) return;
    int s = ei[e];
    int d = ei[N_EDGES + e];
    atomicAdd(deg + s, 1.0f);
    float4 a = x4[(size_t)2 * d];
    float4 b = x4[(size_t)2 * d + 1];
    float* p = agg + (size_t)s * 8;
    atomicAdd(p + 0, a.x); atomicAdd(p + 1, a.y);
    atomicAdd(p + 2, a.z); atomicAdd(p + 3, a.w);
    atomicAdd(p + 4, b.x); atomicAdd(p + 5, b.y);
    atomicAdd(p + 6, b.z); atomicAdd(p + 7, b.w);
}

__device__ __forceinline__ void matvec128(
    const float (&Hin)[NPB][LDP],
    const float* __restrict__ W, const float* __restrict__ bias,
    int n0, int j0, float (&acc)[4][8])
{
    {
        float4 bb0 = *(const float4*)(bias + j0);
        float4 bb1 = *(const float4*)(bias + j0 + 4);
        #pragma unroll
        for (int r = 0; r < 4; ++r) {
            acc[r][0] = bb0.x; acc[r][1] = bb0.y; acc[r][2] = bb0.z; acc[r][3] = bb0.w;
            acc[r][4] = bb1.x; acc[r][5] = bb1.y; acc[r][6] = bb1.z; acc[r][7] = bb1.w;
        }
    }
    for (int k = 0; k < 128; k += 4) {
        float h[4][4];
        #pragma unroll
        for (int r = 0; r < 4; ++r) {
            float4 hv = *(const float4*)&Hin[n0 + r][k];
            h[r][0] = hv.x; h[r][1] = hv.y; h[r][2] = hv.z; h[r][3] = hv.w;
        }
        #pragma unroll
        for (int kk = 0; kk < 4; ++kk) {
            const float* wr = W + (size_t)(k + kk) * HID + j0;
            float4 w0 = *(const float4*)(wr);
            float4 w1 = *(const float4*)(wr + 4);
            float w[8] = {w0.x, w0.y, w0.z, w0.w, w1.x, w1.y, w1.z, w1.w};
            #pragma unroll
            for (int r = 0; r < 4; ++r) {
                float hv = h[r][kk];
                #pragma unroll
                for (int c = 0; c < 8; ++c)
                    acc[r][c] = fmaf(hv, w[c], acc[r][c]);
            }
        }
    }
}

__global__ __launch_bounds__(256, 4) void k_mlp(
    const float4* __restrict__ x4, const float4* __restrict__ agg4,
    const float* __restrict__ degf,
    const float* __restrict__ W1, const float* __restrict__ b1,
    const float* __restrict__ W2, const float* __restrict__ b2,
    const float* __restrict__ W3, const float* __restrict__ b3,
    float* __restrict__ colsum)
{
    __shared__ float A[NPB][LDP];
    __shared__ float csum[HID];

    int tid  = threadIdx.x;
    int cidx = tid & 15;
    int nidx = tid >> 4;
    int j0 = cidx * 8;
    int n0 = nidx * 4;
    int nbase = blockIdx.x * NPB;

    if (tid < HID) csum[tid] = 0.0f;

    float v[4][8];
    #pragma unroll
    for (int r = 0; r < 4; ++r) {
        int gn = nbase + n0 + r;
        if (gn < N_NODES) {
            float4 xa = x4[(size_t)2 * gn], xb = x4[(size_t)2 * gn + 1];
            float4 aa = agg4[(size_t)2 * gn], ab = agg4[(size_t)2 * gn + 1];
            float rd = 1.0f / fmaxf(degf[gn], 1.0f);
            v[r][0] = xa.x + aa.x * rd; v[r][1] = xa.y + aa.y * rd;
            v[r][2] = xa.z + aa.z * rd; v[r][3] = xa.w + aa.w * rd;
            v[r][4] = xb.x + ab.x * rd; v[r][5] = xb.y + ab.y * rd;
            v[r][6] = xb.z + ab.z * rd; v[r][7] = xb.w + ab.w * rd;
        } else {
            #pragma unroll
            for (int k = 0; k < 8; ++k) v[r][k] = 0.0f;
        }
    }

    float acc[4][8];
    {
        float4 bb0 = *(const float4*)(b1 + j0);
        float4 bb1 = *(const float4*)(b1 + j0 + 4);
        #pragma unroll
        for (int r = 0; r < 4; ++r) {
            acc[r][0] = bb0.x; acc[r][1] = bb0.y; acc[r][2] = bb0.z; acc[r][3] = bb0.w;
            acc[r][4] = bb1.x; acc[r][5] = bb1.y; acc[r][6] = bb1.z; acc[r][7] = bb1.w;
        }
    }
    #pragma unroll
    for (int k = 0; k < 8; ++k) {
        const float* wr = W1 + (size_t)k * HID + j0;
        float4 w0 = *(const float4*)(wr);
        float4 w1 = *(const float4*)(wr + 4);
        float w[8] = {w0.x, w0.y, w0.z, w0.w, w1.x, w1.y, w1.z, w1.w};
        #pragma unroll
        for (int r = 0; r < 4; ++r) {
            float hv = v[r][k];
            #pragma unroll
            for (int c = 0; c < 8; ++c) acc[r][c] = fmaf(hv, w[c], acc[r][c]);
        }
    }
    #pragma unroll
    for (int r = 0; r < 4; ++r) {
        *(float4*)&A[n0 + r][j0] = make_float4(
            fmaxf(acc[r][0], 0.f), fmaxf(acc[r][1], 0.f),
            fmaxf(acc[r][2], 0.f), fmaxf(acc[r][3], 0.f));
        *(float4*)&A[n0 + r][j0 + 4] = make_float4(
            fmaxf(acc[r][4], 0.f), fmaxf(acc[r][5], 0.f),
            fmaxf(acc[r][6], 0.f), fmaxf(acc[r][7], 0.f));
    }
    __syncthreads();

    matvec128(A, W2, b2, n0, j0, acc);
    __syncthreads();
    #pragma unroll
    for (int r = 0; r < 4; ++r) {
        *(float4*)&A[n0 + r][j0] = make_float4(
            fmaxf(acc[r][0], 0.f), fmaxf(acc[r][1], 0.f),
            fmaxf(acc[r][2], 0.f), fmaxf(acc[r][3], 0.f));
        *(float4*)&A[n0 + r][j0 + 4] = make_float4(
            fmaxf(acc[r][4], 0.f), fmaxf(acc[r][5], 0.f),
            fmaxf(acc[r][6], 0.f), fmaxf(acc[r][7], 0.f));
    }
    __syncthreads();

    matvec128(A, W3, b3, n0, j0, acc);

    float part[8];
    #pragma unroll
    for (int c = 0; c < 8; ++c) part[c] = 0.0f;
    #pragma unroll
    for (int r = 0; r < 4; ++r) {
        if (nbase + n0 + r < N_NODES) {
            #pragma unroll
            for (int c = 0; c < 8; ++c) part[c] += fmaxf(acc[r][c], 0.f);
        }
    }
    #pragma unroll
    for (int c = 0; c < 8; ++c) atomicAdd(&csum[j0 + c], part[c]);
    __syncthreads();
    if (tid < HID) atomicAdd(colsum + tid, csum[tid]);
}

__global__ void k_final(const float* __restrict__ colsum,
                        const float* __restrict__ Wv, const float* __restrict__ bv,
                        float* __restrict__ out)
{
    __shared__ float red[2];
    int t = threadIdx.x;  // 128 threads
    float vv = colsum[t] * (1.0f / (float)N_NODES) * Wv[t];
    #pragma unroll
    for (int m = 32; m >= 1; m >>= 1) vv += __shfl_xor(vv, m, 64);
    if ((t & 63) == 0) red[t >> 6] = vv;
    __syncthreads();
    if (t == 0) out[0] = tanhf(red[0] + red[1] + bv[0]);
}

extern "C" void kernel_launch(void* const* d_in, const int* in_sizes, int n_in,
                              void* d_out, int out_size, void* d_ws, size_t ws_size,
                              hipStream_t stream)
{
    const float* x  = (const float*)d_in[0];
    const int*   ei = (const int*)d_in[1];
    const float* W1 = (const float*)d_in[2];
    const float* b1 = (const float*)d_in[3];
    const float* W2 = (const float*)d_in[4];
    const float* b2 = (const float*)d_in[5];
    const float* W3 = (const float*)d_in[6];
    const float* b3 = (const float*)d_in[7];
    const float* Wv = (const float*)d_in[8];
    const float* bv = (const float*)d_in[9];
    float* out = (float*)d_out;

    char* ws = (char*)d_ws;
    const size_t OFF_GCNT   = 0;
    const size_t OFF_COLSUM = 4096;
    const size_t OFF_DEGX   = 4608;
    const size_t OFF_AGGX   = 2004608;
    const size_t OFF_REGION = 18004608;
    const size_t OFF_AGG    = 54020736;
    const size_t OFF_DEGF   = 70020736;
    const size_t OFF_XH     = 72020736;
    const size_t OFF_PACK1  = 80020736;
    const size_t OFF_PACK2  = 80037120;
    const size_t OFF_PACK3  = 80102656;
    const size_t WS_NEED    = 80168192;

    if (ws_size >= WS_NEED) {
        int*      gcnt   = (int*)(ws + OFF_GCNT);
        float*    colsum = (float*)(ws + OFF_COLSUM);
        float*    degx   = (float*)(ws + OFF_DEGX);
        float*    aggx   = (float*)(ws + OFF_AGGX);
        unsigned* region = (unsigned*)(ws + OFF_REGION);
        float*    agg    = (float*)(ws + OFF_AGG);
        float*    degf   = (float*)(ws + OFF_DEGF);
        uint4*    xh     = (uint4*)(ws + OFF_XH);
        ushort*   P1     = (ushort*)(ws + OFF_PACK1);
        ushort*   P2     = (ushort*)(ws + OFF_PACK2);
        ushort*   P3     = (ushort*)(ws + OFF_PACK3);

        hipMemsetAsync(ws, 0, OFF_REGION, stream);  // gcnt+colsum+extras

        k_xhalf<<<(N_NODES + 255) / 256, 256, 0, stream>>>((const float4*)x, xh);

        k_pack<<<3, 256, 0, stream>>>(W1, W2, W3, P1, P2, P3);

        k_bin<<<(N_EDGES + EPB - 1) / EPB, 256, 0, stream>>>(
            ei, (const float4*)x, gcnt, region, aggx, degx);

        k_gather<<<NBUCK, 512, 0, stream>>>(
            region, gcnt, xh,
            (const float4*)aggx, degx, (float4*)agg, degf);

        k_mlp_mfma<<<(N_NODES + MNPB - 1) / MNPB, 512, 0, stream>>>(
            (const float4*)x, (const float4*)agg, degf,
            P1, b1, P2, b2, P3, b3, colsum);

        k_final<<<1, 128, 0, stream>>>(colsum, Wv, bv, out);
    } else {
        float* agg    = (float*)(ws);
        float* deg    = (float*)(ws + (size_t)N_NODES * 8 * 4);
        float* colsum = (float*)(ws + (size_t)N_NODES * 8 * 4 + (size_t)N_NODES * 4);
        size_t zero_bytes = (size_t)N_NODES * 8 * 4 + (size_t)N_NODES * 4 + HID * 4;

        hipMemsetAsync(d_ws, 0, zero_bytes, stream);

        k_scatter<<<(N_EDGES + 255) / 256, 256, 0, stream>>>(
            ei, (const float4*)x, agg, deg);

        k_mlp<<<(N_NODES + NPB - 1) / NPB, 256, 0, stream>>>(
            (const float4*)x, (const float4*)agg, deg,
            W1, b1, W2, b2, W3, b3, colsum);

        k_final<<<1, 128, 0, stream>>>(colsum, Wv, bv, out);
    }
}

// Round 13
// 379.694 us; speedup vs baseline: 2.0547x; 2.0547x over previous
//
#include <hip/hip_runtime.h>
#include <hip/hip_bf16.h>
#include <hip/hip_fp16.h>

#define N_NODES 500000
#define N_EDGES 8000000
#define HID 128
#define NPB 64       // nodes per block in fallback MLP kernel
#define LDP 132      // padded LDS row (floats) for fallback

#define BSH 9        // 512 nodes per bucket
#define BNODES 512
#define NBUCK 977    // ceil(500000/512)
#define CAPB 9216    // slots per bucket region
#define EPB 16384    // edges per binning block
#define DSTMASK 0x7FFFFu

#define MNPB 128     // nodes per block in MFMA MLP (4 waves x 32 rows)
#define HPAD 136     // padded H row in bf16 elems (272B, 16B-aligned rows)

typedef __attribute__((ext_vector_type(8))) short bf16x8;
typedef __attribute__((ext_vector_type(4))) float f32x4;

__device__ __forceinline__ ushort f2bf(float f) {
    unsigned u = __float_as_uint(f);
    return (ushort)((u + 0x7fffu + ((u >> 16) & 1u)) >> 16);   // RNE
}
__device__ __forceinline__ float bf2f(ushort h) {
    return __uint_as_float((unsigned)h << 16);
}
// pack 2 f32 -> 2 bf16 in one u32 (lo->bits[15:0], hi->bits[31:16])
__device__ __forceinline__ unsigned cvt_pk_bf16(float lo, float hi) {
    unsigned r;
    asm("v_cvt_pk_bf16_f32 %0, %1, %2" : "=v"(r) : "v"(lo), "v"(hi));
    return r;
}

// ---------------------------------------------------------------------------
// Fast-path workspace layout (bytes), needs 80,168,192:
//   [0, 4,096)                 gcnt      int[NBUCK]         (zeroed)
//   [4,096, 4,608)             colsum    float[128]         (zeroed)
//   [4,608, 2,004,608)         deg_extra float[N_NODES]     (zeroed)
//   [2,004,608, 18,004,608)    agg_extra float[N_NODES*8]   (zeroed)
//   [18,004,608, 54,020,736)   region    u32[NBUCK*CAPB]
//   [54,020,736, 70,020,736)   agg       float[N_NODES*8]
//   [70,020,736, 72,020,736)   degf      float[N_NODES]
//   [72,020,736, 80,020,736)   xh        half[N_NODES*8]
//   [80,020,736, 80,037,120)   P1 packed W1 bf16 hi/lo frags
//   [80,037,120, 80,102,656)   P2 packed W2
//   [80,102,656, 80,168,192)   P3 packed W3
// ---------------------------------------------------------------------------

// ---- x -> fp16 shadow copy (16 B per node) --------------------------------
__global__ __launch_bounds__(256) void k_xhalf(
    const float4* __restrict__ x4, uint4* __restrict__ xh)
{
    int n = blockIdx.x * 256 + threadIdx.x;
    if (n >= N_NODES) return;
    float4 a = x4[(size_t)2 * n], b = x4[(size_t)2 * n + 1];
    __half2 p0 = __floats2half2_rn(a.x, a.y);
    __half2 p1 = __floats2half2_rn(a.z, a.w);
    __half2 p2 = __floats2half2_rn(b.x, b.y);
    __half2 p3 = __floats2half2_rn(b.z, b.w);
    uint4 o;
    o.x = *(unsigned*)&p0; o.y = *(unsigned*)&p1;
    o.z = *(unsigned*)&p2; o.w = *(unsigned*)&p3;
    xh[n] = o;
}

// ---- phase 1: bin edges by src bucket -------------------------------------
__global__ __launch_bounds__(256) void k_bin(
    const int* __restrict__ ei, const float4* __restrict__ x4,
    int* __restrict__ gcnt, unsigned* __restrict__ region,
    float* __restrict__ agg_extra, float* __restrict__ deg_extra)
{
    __shared__ int cntA[NBUCK];
    __shared__ int baseB[NBUCK];
    int tid = threadIdx.x;
    for (int b = tid; b < NBUCK; b += 256) cntA[b] = 0;
    __syncthreads();
    int e0 = blockIdx.x * EPB;

    // pass A: per-block bucket histogram (vectorized int4 reads)
    #pragma unroll 4
    for (int k = 0; k < EPB / 1024; ++k) {
        int e = e0 + k * 1024 + tid * 4;
        if (e + 3 < N_EDGES) {
            int4 s4 = *(const int4*)(ei + e);
            atomicAdd(&cntA[s4.x >> BSH], 1);
            atomicAdd(&cntA[s4.y >> BSH], 1);
            atomicAdd(&cntA[s4.z >> BSH], 1);
            atomicAdd(&cntA[s4.w >> BSH], 1);
        } else {
            for (int j = 0; j < 4; ++j)
                if (e + j < N_EDGES) atomicAdd(&cntA[ei[e + j] >> BSH], 1);
        }
    }
    __syncthreads();

    // reserve global ranges: one global atomic per (block, bucket)
    for (int b = tid; b < NBUCK; b += 256) {
        int c = cntA[b];
        baseB[b] = (c > 0) ? atomicAdd(&gcnt[b], c) : 0;
        cntA[b] = 0;
    }
    __syncthreads();

    // pass B: place edges
    #pragma unroll 2
    for (int k = 0; k < EPB / 1024; ++k) {
        int e = e0 + k * 1024 + tid * 4;
        if (e + 3 < N_EDGES) {
            int4 s4 = *(const int4*)(ei + e);
            int4 d4 = *(const int4*)(ei + N_EDGES + e);
            int ss[4] = {s4.x, s4.y, s4.z, s4.w};
            int dd[4] = {d4.x, d4.y, d4.z, d4.w};
            #pragma unroll
            for (int j = 0; j < 4; ++j) {
                int s = ss[j], d = dd[j];
                int b = s >> BSH;
                int pos = atomicAdd(&cntA[b], 1);
                int slot = baseB[b] + pos;
                if (slot < CAPB) {
                    region[(size_t)b * CAPB + slot] =
                        ((unsigned)(s & (BNODES - 1)) << 19) | (unsigned)d;
                } else {
                    float4 a = x4[(size_t)2 * d];
                    float4 bb = x4[(size_t)2 * d + 1];
                    float* p = agg_extra + (size_t)s * 8;
                    atomicAdd(p + 0, a.x); atomicAdd(p + 1, a.y);
                    atomicAdd(p + 2, a.z); atomicAdd(p + 3, a.w);
                    atomicAdd(p + 4, bb.x); atomicAdd(p + 5, bb.y);
                    atomicAdd(p + 6, bb.z); atomicAdd(p + 7, bb.w);
                    atomicAdd(deg_extra + s, 1.0f);
                }
            }
        } else {
            for (int j = 0; j < 4; ++j) {
                if (e + j >= N_EDGES) break;
                int s = ei[e + j], d = ei[N_EDGES + e + j];
                int b = s >> BSH;
                int pos = atomicAdd(&cntA[b], 1);
                int slot = baseB[b] + pos;
                if (slot < CAPB) {
                    region[(size_t)b * CAPB + slot] =
                        ((unsigned)(s & (BNODES - 1)) << 19) | (unsigned)d;
                } else {
                    float4 a = x4[(size_t)2 * d];
                    float4 bb = x4[(size_t)2 * d + 1];
                    float* p = agg_extra + (size_t)s * 8;
                    atomicAdd(p + 0, a.x); atomicAdd(p + 1, a.y);
                    atomicAdd(p + 2, a.z); atomicAdd(p + 3, a.w);
                    atomicAdd(p + 4, bb.x); atomicAdd(p + 5, bb.y);
                    atomicAdd(p + 6, bb.z); atomicAdd(p + 7, bb.w);
                    atomicAdd(deg_extra + s, 1.0f);
                }
            }
        }
    }
}

// ---- phase 2: per-bucket counting sort + register accumulate --------------
__device__ __forceinline__ void addx(float* s, uint4 v) {
    const __half2* h = (const __half2*)&v;
    #pragma unroll
    for (int c = 0; c < 4; ++c) {
        float2 f = __half22float2(h[c]);
        s[2 * c]     += f.x;
        s[2 * c + 1] += f.y;
    }
}

__global__ __launch_bounds__(512) void k_gather(
    const unsigned* __restrict__ region, const int* __restrict__ gcnt,
    const uint4* __restrict__ xh,
    const float4* __restrict__ agg_extra4, const float* __restrict__ deg_extra,
    float4* __restrict__ agg4, float* __restrict__ degf)
{
    __shared__ unsigned sorted[CAPB];    // 36.9 KB
    __shared__ int cnt[BNODES];          // histogram (preserved)
    __shared__ int scan[BNODES];         // inclusive scan
    __shared__ int run[BNODES];          // scatter cursors
    int tid = threadIdx.x;
    int b = blockIdx.x;

    cnt[tid] = 0;
    run[tid] = 0;
    __syncthreads();

    int ne = gcnt[b];
    if (ne > CAPB) ne = CAPB;
    const unsigned* reg = region + (size_t)b * CAPB;

    // pass 1: histogram of local src (1 LDS atomic/edge)
    for (int i = tid; i < ne; i += 512)
        atomicAdd(&cnt[reg[i] >> 19], 1);
    __syncthreads();

    // inclusive Hillis-Steele scan over 512 counts
    scan[tid] = cnt[tid];
    __syncthreads();
    #pragma unroll
    for (int s = 1; s < BNODES; s <<= 1) {
        int v = (tid >= s) ? scan[tid - s] : 0;
        __syncthreads();
        scan[tid] += v;
        __syncthreads();
    }

    // pass 2: scatter dst ids to per-node contiguous runs (1 LDS atomic/edge)
    for (int i = tid; i < ne; i += 512) {
        unsigned p = reg[i];
        int ls = (int)(p >> 19);
        int pos = atomicAdd(&run[ls], 1);
        sorted[(scan[ls] - cnt[ls]) + pos] = p & DSTMASK;
    }
    __syncthreads();

    // pass 3: one thread per node, register accumulation (no atomics),
    // 8 independent gathers in flight
    int deg  = cnt[tid];
    int base = scan[tid] - cnt[tid];
    float s[8];
    #pragma unroll
    for (int c = 0; c < 8; ++c) s[c] = 0.0f;

    int j = 0;
    for (; j + 8 <= deg; j += 8) {
        uint4 xv[8];
        #pragma unroll
        for (int q = 0; q < 8; ++q) xv[q] = xh[sorted[base + j + q]];
        #pragma unroll
        for (int q = 0; q < 8; ++q) addx(s, xv[q]);
    }
    for (; j + 4 <= deg; j += 4) {
        uint4 x0 = xh[sorted[base + j]];
        uint4 x1 = xh[sorted[base + j + 1]];
        uint4 x2 = xh[sorted[base + j + 2]];
        uint4 x3 = xh[sorted[base + j + 3]];
        addx(s, x0); addx(s, x1); addx(s, x2); addx(s, x3);
    }
    for (; j < deg; ++j) {
        uint4 xv = xh[sorted[base + j]];
        addx(s, xv);
    }

    int gn = b * BNODES + tid;
    if (gn < N_NODES) {
        float4 e0 = agg_extra4[(size_t)2 * gn];
        float4 e1 = agg_extra4[(size_t)2 * gn + 1];
        agg4[(size_t)2 * gn] = make_float4(
            s[0] + e0.x, s[1] + e0.y, s[2] + e0.z, s[3] + e0.w);
        agg4[(size_t)2 * gn + 1] = make_float4(
            s[4] + e1.x, s[5] + e1.y, s[6] + e1.z, s[7] + e1.w);
        degf[gn] = (float)deg + deg_extra[gn];
    }
}

// ---- pack W into MFMA B-fragment order, split bf16 hi/lo ------------------
// Layout: P[(ks*8+ct)*2 + hl][lane 0..63][j 0..7]  (ushort)
__global__ __launch_bounds__(256) void k_pack(
    const float* __restrict__ W1, const float* __restrict__ W2,
    const float* __restrict__ W3,
    ushort* __restrict__ P1, ushort* __restrict__ P2, ushort* __restrict__ P3)
{
    int b = blockIdx.x;
    const float* W = (b == 0) ? W1 : ((b == 1) ? W2 : W3);
    ushort* P = (b == 0) ? P1 : ((b == 1) ? P2 : P3);
    int KS = (b == 0) ? 1 : 4;
    int total = KS * 8 * 64 * 8;
    for (int i = threadIdx.x; i < total; i += 256) {
        int j    = i & 7;
        int lane = (i >> 3) & 63;
        int ct   = (i >> 9) & 7;
        int ks   = i >> 12;
        int k = ks * 32 + (lane >> 4) * 8 + j;
        int c = ct * 16 + (lane & 15);
        float wv = 0.0f;
        if (b == 0) { if (k < 8) wv = W[k * HID + c]; }
        else        { wv = W[k * HID + c]; }
        ushort hi = f2bf(wv);
        float  lo = wv - bf2f(hi);
        P[(((ks * 8 + ct) * 2 + 0) * 64 + lane) * 8 + j] = hi;
        P[(((ks * 8 + ct) * 2 + 1) * 64 + lane) * 8 + j] = f2bf(lo);
    }
}

// ---- one MFMA layer, 32 rows/wave, 6-deep rolling B buffer ----------------
// Quad q: ks=q>>2, grp=(q>>1)&1, hl=q&1, frags f=0..3 -> ct=grp*4+f.
// NO sched_barrier (r12: order-pinning under a tight VGPR cap forces scratch
// spill). Here __launch_bounds__(256,2) gives a 256-VGPR budget so the
// allocator CAN keep B[6][4]=96 regs live; trust its scheduler.
template<int KS, bool STORE>
__device__ __forceinline__ void mfma_layer(
    ushort (&H)[MNPB][HPAD],
    const ushort* __restrict__ P, const float* __restrict__ bias,
    int rbase, int l, float* csum, int nbase)
{
    const int cl = l & 15;
    const int g  = l >> 4;
    constexpr int NQ = KS * 4;
    constexpr int DEPTH = (NQ < 6) ? NQ : 6;

    f32x4 acc[8][2];
    #pragma unroll
    for (int ct = 0; ct < 8; ++ct) {
        float bv = bias[ct * 16 + cl];
        f32x4 b4 = {bv, bv, bv, bv};
        acc[ct][0] = b4;
        acc[ct][1] = b4;
    }

    // all A fragments up front (LDS; one lgkm region)
    bf16x8 A0[KS], A1[KS];
    #pragma unroll
    for (int ks = 0; ks < KS; ++ks) {
        int col = ks * 32 + g * 8;
        A0[ks] = *(const bf16x8*)&H[rbase + cl][col];
        A1[ks] = *(const bf16x8*)&H[rbase + 16 + cl][col];
    }

    bf16x8 B[DEPTH][4];     // DEPTH-quad rolling buffer (96 VGPR at DEPTH=6)
    #pragma unroll
    for (int q = 0; q < DEPTH; ++q) {
        #pragma unroll
        for (int f = 0; f < 4; ++f)
            B[q][f] = *(const bf16x8*)(P +
                (size_t)(((q >> 2) * 8 + ((q >> 1) & 1) * 4 + f) * 1024
                         + (q & 1) * 512 + l * 8));
    }

    #pragma unroll
    for (int q = 0; q < NQ; ++q) {
        const int ks  = q >> 2;
        const int grp = (q >> 1) & 1;
        const int buf = q % DEPTH;
        #pragma unroll
        for (int f = 0; f < 4; ++f) {
            const int ct = grp * 4 + f;
            acc[ct][0] = __builtin_amdgcn_mfma_f32_16x16x32_bf16(A0[ks], B[buf][f], acc[ct][0], 0, 0, 0);
            acc[ct][1] = __builtin_amdgcn_mfma_f32_16x16x32_bf16(A1[ks], B[buf][f], acc[ct][1], 0, 0, 0);
        }
        if (q + DEPTH < NQ) {
            const int qn = q + DEPTH;
            #pragma unroll
            for (int f = 0; f < 4; ++f)
                B[buf][f] = *(const bf16x8*)(P +
                    (size_t)(((qn >> 2) * 8 + ((qn >> 1) & 1) * 4 + f) * 1024
                             + (qn & 1) * 512 + l * 8));
        }
    }

    if (STORE) {
        #pragma unroll
        for (int ct = 0; ct < 8; ++ct) {
            #pragma unroll
            for (int rt = 0; rt < 2; ++rt) {
                f32x4 a = acc[ct][rt];
                unsigned p0 = cvt_pk_bf16(fmaxf(a[0], 0.f), fmaxf(a[1], 0.f));
                unsigned p1 = cvt_pk_bf16(fmaxf(a[2], 0.f), fmaxf(a[3], 0.f));
                int r0 = rbase + rt * 16 + g * 4;
                int c  = ct * 16 + cl;
                H[r0 + 0][c] = (ushort)p0;
                H[r0 + 1][c] = (ushort)(p0 >> 16);
                H[r0 + 2][c] = (ushort)p1;
                H[r0 + 3][c] = (ushort)(p1 >> 16);
            }
        }
    } else {
        #pragma unroll
        for (int ct = 0; ct < 8; ++ct) {
            float part = 0.0f;
            #pragma unroll
            for (int rt = 0; rt < 2; ++rt) {
                f32x4 a = acc[ct][rt];
                #pragma unroll
                for (int j = 0; j < 4; ++j) {
                    int gn = nbase + rbase + rt * 16 + g * 4 + j;
                    float h = fmaxf(a[j], 0.0f);
                    part += (gn < N_NODES) ? h : 0.0f;
                }
            }
            part += __shfl_xor(part, 16, 64);
            part += __shfl_xor(part, 32, 64);
            if (g == 0) atomicAdd(&csum[ct * 16 + cl], part);
        }
    }
}

// ---- fused 3-layer MLP: 4 waves x 32 rows, 256-VGPR budget, deep ILP ------
__global__ __launch_bounds__(256, 2) void k_mlp_mfma(
    const float4* __restrict__ x4, const float4* __restrict__ agg4,
    const float* __restrict__ degf,
    const ushort* __restrict__ P1, const float* __restrict__ b1,
    const ushort* __restrict__ P2, const float* __restrict__ b2,
    const ushort* __restrict__ P3, const float* __restrict__ b3,
    float* __restrict__ colsum)
{
    __shared__ ushort H[MNPB][HPAD];    // 34.8 KB
    __shared__ float csum[HID];

    const int tid = threadIdx.x;        // 0..255
    const int wv  = tid >> 6;           // 0..3
    const int l   = tid & 63;
    const int rbase = wv * 32;          // wave owns rows [rbase, rbase+32)
    const int nbase = blockIdx.x * MNPB;

    if (tid < HID) csum[tid] = 0.0f;
    __syncthreads();

    if (l < 32) {
        int rr = l;
        int gn = nbase + rbase + rr;
        float vv[8];
        if (gn < N_NODES) {
            float4 xa = x4[(size_t)2 * gn], xb = x4[(size_t)2 * gn + 1];
            float4 a0 = agg4[(size_t)2 * gn];
            float4 a1 = agg4[(size_t)2 * gn + 1];
            float rd = 1.0f / fmaxf(degf[gn], 1.0f);
            vv[0] = xa.x + a0.x * rd; vv[1] = xa.y + a0.y * rd;
            vv[2] = xa.z + a0.z * rd; vv[3] = xa.w + a0.w * rd;
            vv[4] = xb.x + a1.x * rd; vv[5] = xb.y + a1.y * rd;
            vv[6] = xb.z + a1.z * rd; vv[7] = xb.w + a1.w * rd;
        } else {
            #pragma unroll
            for (int j = 0; j < 8; ++j) vv[j] = 0.0f;
        }
        uint4 hv;
        hv.x = cvt_pk_bf16(vv[0], vv[1]);
        hv.y = cvt_pk_bf16(vv[2], vv[3]);
        hv.z = cvt_pk_bf16(vv[4], vv[5]);
        hv.w = cvt_pk_bf16(vv[6], vv[7]);
        int row = rbase + rr;
        uint4 z = {0, 0, 0, 0};
        *(uint4*)&H[row][0]  = hv;
        *(uint4*)&H[row][8]  = z;
        *(uint4*)&H[row][16] = z;
        *(uint4*)&H[row][24] = z;
    }
    // layer dataflow is wave-local; the barriers below are phase-alignment
    // only (waves stream the same W fragments in lockstep -> L1 line reuse)

    mfma_layer<1, true >(H, P1, b1, rbase, l, csum, nbase);  // 8 -> 128
    __syncthreads();
    mfma_layer<4, true >(H, P2, b2, rbase, l, csum, nbase);  // 128 -> 128
    __syncthreads();
    mfma_layer<4, false>(H, P3, b3, rbase, l, csum, nbase);  // 128 -> 128 + reduce

    __syncthreads();
    if (tid < HID) atomicAdd(&colsum[tid], csum[tid]);
}

// ---- fallback path kernels (ws too small) ---------------------------------
__global__ __launch_bounds__(256) void k_scatter(
    const int* __restrict__ ei, const float4* __restrict__ x4,
    float* __restrict__ agg, float* __restrict__ deg)
{
    int e = blockIdx.x * 256 + threadIdx.x;
    if (e >= N_EDGES) return;
    int s = ei[e];
    int d = ei[N_EDGES + e];
    atomicAdd(deg + s, 1.0f);
    float4 a = x4[(size_t)2 * d];
    float4 b = x4[(size_t)2 * d + 1];
    float* p = agg + (size_t)s * 8;
    atomicAdd(p + 0, a.x); atomicAdd(p + 1, a.y);
    atomicAdd(p + 2, a.z); atomicAdd(p + 3, a.w);
    atomicAdd(p + 4, b.x); atomicAdd(p + 5, b.y);
    atomicAdd(p + 6, b.z); atomicAdd(p + 7, b.w);
}

__device__ __forceinline__ void matvec128(
    const float (&Hin)[NPB][LDP],
    const float* __restrict__ W, const float* __restrict__ bias,
    int n0, int j0, float (&acc)[4][8])
{
    {
        float4 bb0 = *(const float4*)(bias + j0);
        float4 bb1 = *(const float4*)(bias + j0 + 4);
        #pragma unroll
        for (int r = 0; r < 4; ++r) {
            acc[r][0] = bb0.x; acc[r][1] = bb0.y; acc[r][2] = bb0.z; acc[r][3] = bb0.w;
            acc[r][4] = bb1.x; acc[r][5] = bb1.y; acc[r][6] = bb1.z; acc[r][7] = bb1.w;
        }
    }
    for (int k = 0; k < 128; k += 4) {
        float h[4][4];
        #pragma unroll
        for (int r = 0; r < 4; ++r) {
            float4 hv = *(const float4*)&Hin[n0 + r][k];
            h[r][0] = hv.x; h[r][1] = hv.y; h[r][2] = hv.z; h[r][3] = hv.w;
        }
        #pragma unroll
        for (int kk = 0; kk < 4; ++kk) {
            const float* wr = W + (size_t)(k + kk) * HID + j0;
            float4 w0 = *(const float4*)(wr);
            float4 w1 = *(const float4*)(wr + 4);
            float w[8] = {w0.x, w0.y, w0.z, w0.w, w1.x, w1.y, w1.z, w1.w};
            #pragma unroll
            for (int r = 0; r < 4; ++r) {
                float hv = h[r][kk];
                #pragma unroll
                for (int c = 0; c < 8; ++c)
                    acc[r][c] = fmaf(hv, w[c], acc[r][c]);
            }
        }
    }
}

__global__ __launch_bounds__(256, 4) void k_mlp(
    const float4* __restrict__ x4, const float4* __restrict__ agg4,
    const float* __restrict__ degf,
    const float* __restrict__ W1, const float* __restrict__ b1,
    const float* __restrict__ W2, const float* __restrict__ b2,
    const float* __restrict__ W3, const float* __restrict__ b3,
    float* __restrict__ colsum)
{
    __shared__ float A[NPB][LDP];
    __shared__ float csum[HID];

    int tid  = threadIdx.x;
    int cidx = tid & 15;
    int nidx = tid >> 4;
    int j0 = cidx * 8;
    int n0 = nidx * 4;
    int nbase = blockIdx.x * NPB;

    if (tid < HID) csum[tid] = 0.0f;

    float v[4][8];
    #pragma unroll
    for (int r = 0; r < 4; ++r) {
        int gn = nbase + n0 + r;
        if (gn < N_NODES) {
            float4 xa = x4[(size_t)2 * gn], xb = x4[(size_t)2 * gn + 1];
            float4 aa = agg4[(size_t)2 * gn], ab = agg4[(size_t)2 * gn + 1];
            float rd = 1.0f / fmaxf(degf[gn], 1.0f);
            v[r][0] = xa.x + aa.x * rd; v[r][1] = xa.y + aa.y * rd;
            v[r][2] = xa.z + aa.z * rd; v[r][3] = xa.w + aa.w * rd;
            v[r][4] = xb.x + ab.x * rd; v[r][5] = xb.y + ab.y * rd;
            v[r][6] = xb.z + ab.z * rd; v[r][7] = xb.w + ab.w * rd;
        } else {
            #pragma unroll
            for (int k = 0; k < 8; ++k) v[r][k] = 0.0f;
        }
    }

    float acc[4][8];
    {
        float4 bb0 = *(const float4*)(b1 + j0);
        float4 bb1 = *(const float4*)(b1 + j0 + 4);
        #pragma unroll
        for (int r = 0; r < 4; ++r) {
            acc[r][0] = bb0.x; acc[r][1] = bb0.y; acc[r][2] = bb0.z; acc[r][3] = bb0.w;
            acc[r][4] = bb1.x; acc[r][5] = bb1.y; acc[r][6] = bb1.z; acc[r][7] = bb1.w;
        }
    }
    #pragma unroll
    for (int k = 0; k < 8; ++k) {
        const float* wr = W1 + (size_t)k * HID + j0;
        float4 w0 = *(const float4*)(wr);
        float4 w1 = *(const float4*)(wr + 4);
        float w[8] = {w0.x, w0.y, w0.z, w0.w, w1.x, w1.y, w1.z, w1.w};
        #pragma unroll
        for (int r = 0; r < 4; ++r) {
            float hv = v[r][k];
            #pragma unroll
            for (int c = 0; c < 8; ++c) acc[r][c] = fmaf(hv, w[c], acc[r][c]);
        }
    }
    #pragma unroll
    for (int r = 0; r < 4; ++r) {
        *(float4*)&A[n0 + r][j0] = make_float4(
            fmaxf(acc[r][0], 0.f), fmaxf(acc[r][1], 0.f),
            fmaxf(acc[r][2], 0.f), fmaxf(acc[r][3], 0.f));
        *(float4*)&A[n0 + r][j0 + 4] = make_float4(
            fmaxf(acc[r][4], 0.f), fmaxf(acc[r][5], 0.f),
            fmaxf(acc[r][6], 0.f), fmaxf(acc[r][7], 0.f));
    }
    __syncthreads();

    matvec128(A, W2, b2, n0, j0, acc);
    __syncthreads();
    #pragma unroll
    for (int r = 0; r < 4; ++r) {
        *(float4*)&A[n0 + r][j0] = make_float4(
            fmaxf(acc[r][0], 0.f), fmaxf(acc[r][1], 0.f),
            fmaxf(acc[r][2], 0.f), fmaxf(acc[r][3], 0.f));
        *(float4*)&A[n0 + r][j0 + 4] = make_float4(
            fmaxf(acc[r][4], 0.f), fmaxf(acc[r][5], 0.f),
            fmaxf(acc[r][6], 0.f), fmaxf(acc[r][7], 0.f));
    }
    __syncthreads();

    matvec128(A, W3, b3, n0, j0, acc);

    float part[8];
    #pragma unroll
    for (int c = 0; c < 8; ++c) part[c] = 0.0f;
    #pragma unroll
    for (int r = 0; r < 4; ++r) {
        if (nbase + n0 + r < N_NODES) {
            #pragma unroll
            for (int c = 0; c < 8; ++c) part[c] += fmaxf(acc[r][c], 0.f);
        }
    }
    #pragma unroll
    for (int c = 0; c < 8; ++c) atomicAdd(&csum[j0 + c], part[c]);
    __syncthreads();
    if (tid < HID) atomicAdd(colsum + tid, csum[tid]);
}

__global__ void k_final(const float* __restrict__ colsum,
                        const float* __restrict__ Wv, const float* __restrict__ bv,
                        float* __restrict__ out)
{
    __shared__ float red[2];
    int t = threadIdx.x;  // 128 threads
    float vv = colsum[t] * (1.0f / (float)N_NODES) * Wv[t];
    #pragma unroll
    for (int m = 32; m >= 1; m >>= 1) vv += __shfl_xor(vv, m, 64);
    if ((t & 63) == 0) red[t >> 6] = vv;
    __syncthreads();
    if (t == 0) out[0] = tanhf(red[0] + red[1] + bv[0]);
}

extern "C" void kernel_launch(void* const* d_in, const int* in_sizes, int n_in,
                              void* d_out, int out_size, void* d_ws, size_t ws_size,
                              hipStream_t stream)
{
    const float* x  = (const float*)d_in[0];
    const int*   ei = (const int*)d_in[1];
    const float* W1 = (const float*)d_in[2];
    const float* b1 = (const float*)d_in[3];
    const float* W2 = (const float*)d_in[4];
    const float* b2 = (const float*)d_in[5];
    const float* W3 = (const float*)d_in[6];
    const float* b3 = (const float*)d_in[7];
    const float* Wv = (const float*)d_in[8];
    const float* bv = (const float*)d_in[9];
    float* out = (float*)d_out;

    char* ws = (char*)d_ws;
    const size_t OFF_GCNT   = 0;
    const size_t OFF_COLSUM = 4096;
    const size_t OFF_DEGX   = 4608;
    const size_t OFF_AGGX   = 2004608;
    const size_t OFF_REGION = 18004608;
    const size_t OFF_AGG    = 54020736;
    const size_t OFF_DEGF   = 70020736;
    const size_t OFF_XH     = 72020736;
    const size_t OFF_PACK1  = 80020736;
    const size_t OFF_PACK2  = 80037120;
    const size_t OFF_PACK3  = 80102656;
    const size_t WS_NEED    = 80168192;

    if (ws_size >= WS_NEED) {
        int*      gcnt   = (int*)(ws + OFF_GCNT);
        float*    colsum = (float*)(ws + OFF_COLSUM);
        float*    degx   = (float*)(ws + OFF_DEGX);
        float*    aggx   = (float*)(ws + OFF_AGGX);
        unsigned* region = (unsigned*)(ws + OFF_REGION);
        float*    agg    = (float*)(ws + OFF_AGG);
        float*    degf   = (float*)(ws + OFF_DEGF);
        uint4*    xh     = (uint4*)(ws + OFF_XH);
        ushort*   P1     = (ushort*)(ws + OFF_PACK1);
        ushort*   P2     = (ushort*)(ws + OFF_PACK2);
        ushort*   P3     = (ushort*)(ws + OFF_PACK3);

        hipMemsetAsync(ws, 0, OFF_REGION, stream);  // gcnt+colsum+extras

        k_xhalf<<<(N_NODES + 255) / 256, 256, 0, stream>>>((const float4*)x, xh);

        k_pack<<<3, 256, 0, stream>>>(W1, W2, W3, P1, P2, P3);

        k_bin<<<(N_EDGES + EPB - 1) / EPB, 256, 0, stream>>>(
            ei, (const float4*)x, gcnt, region, aggx, degx);

        k_gather<<<NBUCK, 512, 0, stream>>>(
            region, gcnt, xh,
            (const float4*)aggx, degx, (float4*)agg, degf);

        k_mlp_mfma<<<(N_NODES + MNPB - 1) / MNPB, 256, 0, stream>>>(
            (const float4*)x, (const float4*)agg, degf,
            P1, b1, P2, b2, P3, b3, colsum);

        k_final<<<1, 128, 0, stream>>>(colsum, Wv, bv, out);
    } else {
        float* agg    = (float*)(ws);
        float* deg    = (float*)(ws + (size_t)N_NODES * 8 * 4);
        float* colsum = (float*)(ws + (size_t)N_NODES * 8 * 4 + (size_t)N_NODES * 4);
        size_t zero_bytes = (size_t)N_NODES * 8 * 4 + (size_t)N_NODES * 4 + HID * 4;

        hipMemsetAsync(d_ws, 0, zero_bytes, stream);

        k_scatter<<<(N_EDGES + 255) / 256, 256, 0, stream>>>(
            ei, (const float4*)x, agg, deg);

        k_mlp<<<(N_NODES + NPB - 1) / NPB, 256, 0, stream>>>(
            (const float4*)x, (const float4*)agg, deg,
            W1, b1, W2, b2, W3, b3, colsum);

        k_final<<<1, 128, 0, stream>>>(colsum, Wv, bv, out);
    }
}

// Round 14
// 328.367 us; speedup vs baseline: 2.3759x; 1.1563x over previous
//
#include <hip/hip_runtime.h>
#include <hip/hip_bf16.h>
#include <hip/hip_fp16.h>

#define N_NODES 500000
#define N_EDGES 8000000
#define HID 128
#define NPB 64       // nodes per block in fallback MLP kernel
#define LDP 132      // padded LDS row (floats) for fallback

#define BSH 9        // 512 nodes per bucket
#define BNODES 512
#define NBUCK 977    // ceil(500000/512)
#define CAPB 9216    // slots per bucket region
#define EPB 16384    // edges per binning block
#define DSTMASK 0x7FFFFu

#define MNPB 256     // nodes per block in MFMA MLP (8 waves x 32 rows)
#define HPAD 136     // padded H row in bf16 elems (272B; lane-stride 4 banks -> 2-way=free)

typedef __attribute__((ext_vector_type(8))) short bf16x8;
typedef __attribute__((ext_vector_type(4))) float f32x4;

__device__ __forceinline__ ushort f2bf(float f) {
    unsigned u = __float_as_uint(f);
    return (ushort)((u + 0x7fffu + ((u >> 16) & 1u)) >> 16);   // RNE
}
__device__ __forceinline__ float bf2f(ushort h) {
    return __uint_as_float((unsigned)h << 16);
}
// pack 2 f32 -> 2 bf16 in one u32 (lo->bits[15:0], hi->bits[31:16])
__device__ __forceinline__ unsigned cvt_pk_bf16(float lo, float hi) {
    unsigned r;
    asm("v_cvt_pk_bf16_f32 %0, %1, %2" : "=v"(r) : "v"(lo), "v"(hi));
    return r;
}

// ---------------------------------------------------------------------------
// Fast-path workspace layout (bytes), needs 80,168,192:
//   [0, 4,096)                 gcnt      int[NBUCK]         (zeroed)
//   [4,096, 4,608)             colsum    float[128]         (zeroed)
//   [4,608, 2,004,608)         deg_extra float[N_NODES]     (zeroed)
//   [2,004,608, 18,004,608)    agg_extra float[N_NODES*8]   (zeroed)
//   [18,004,608, 54,020,736)   region    u32[NBUCK*CAPB]
//   [54,020,736, 70,020,736)   agg       float[N_NODES*8]
//   [70,020,736, 72,020,736)   degf      float[N_NODES]
//   [72,020,736, 80,020,736)   xh        half[N_NODES*8]
//   [80,020,736, 80,037,120)   P1 packed W1 bf16 hi/lo frags (16 KB)
//   [80,037,120, 80,102,656)   P2 packed W2 (64 KB)
//   [80,102,656, 80,168,192)   P3 packed W3 (64 KB)
// ---------------------------------------------------------------------------

// ---- x -> fp16 shadow copy (16 B per node) --------------------------------
__global__ __launch_bounds__(256) void k_xhalf(
    const float4* __restrict__ x4, uint4* __restrict__ xh)
{
    int n = blockIdx.x * 256 + threadIdx.x;
    if (n >= N_NODES) return;
    float4 a = x4[(size_t)2 * n], b = x4[(size_t)2 * n + 1];
    __half2 p0 = __floats2half2_rn(a.x, a.y);
    __half2 p1 = __floats2half2_rn(a.z, a.w);
    __half2 p2 = __floats2half2_rn(b.x, b.y);
    __half2 p3 = __floats2half2_rn(b.z, b.w);
    uint4 o;
    o.x = *(unsigned*)&p0; o.y = *(unsigned*)&p1;
    o.z = *(unsigned*)&p2; o.w = *(unsigned*)&p3;
    xh[n] = o;
}

// ---- phase 1: bin edges by src bucket -------------------------------------
__global__ __launch_bounds__(256) void k_bin(
    const int* __restrict__ ei, const float4* __restrict__ x4,
    int* __restrict__ gcnt, unsigned* __restrict__ region,
    float* __restrict__ agg_extra, float* __restrict__ deg_extra)
{
    __shared__ int cntA[NBUCK];
    __shared__ int baseB[NBUCK];
    int tid = threadIdx.x;
    for (int b = tid; b < NBUCK; b += 256) cntA[b] = 0;
    __syncthreads();
    int e0 = blockIdx.x * EPB;

    // pass A: per-block bucket histogram (vectorized int4 reads)
    #pragma unroll 4
    for (int k = 0; k < EPB / 1024; ++k) {
        int e = e0 + k * 1024 + tid * 4;
        if (e + 3 < N_EDGES) {
            int4 s4 = *(const int4*)(ei + e);
            atomicAdd(&cntA[s4.x >> BSH], 1);
            atomicAdd(&cntA[s4.y >> BSH], 1);
            atomicAdd(&cntA[s4.z >> BSH], 1);
            atomicAdd(&cntA[s4.w >> BSH], 1);
        } else {
            for (int j = 0; j < 4; ++j)
                if (e + j < N_EDGES) atomicAdd(&cntA[ei[e + j] >> BSH], 1);
        }
    }
    __syncthreads();

    // reserve global ranges: one global atomic per (block, bucket)
    for (int b = tid; b < NBUCK; b += 256) {
        int c = cntA[b];
        baseB[b] = (c > 0) ? atomicAdd(&gcnt[b], c) : 0;
        cntA[b] = 0;
    }
    __syncthreads();

    // pass B: place edges
    #pragma unroll 2
    for (int k = 0; k < EPB / 1024; ++k) {
        int e = e0 + k * 1024 + tid * 4;
        if (e + 3 < N_EDGES) {
            int4 s4 = *(const int4*)(ei + e);
            int4 d4 = *(const int4*)(ei + N_EDGES + e);
            int ss[4] = {s4.x, s4.y, s4.z, s4.w};
            int dd[4] = {d4.x, d4.y, d4.z, d4.w};
            #pragma unroll
            for (int j = 0; j < 4; ++j) {
                int s = ss[j], d = dd[j];
                int b = s >> BSH;
                int pos = atomicAdd(&cntA[b], 1);
                int slot = baseB[b] + pos;
                if (slot < CAPB) {
                    region[(size_t)b * CAPB + slot] =
                        ((unsigned)(s & (BNODES - 1)) << 19) | (unsigned)d;
                } else {
                    float4 a = x4[(size_t)2 * d];
                    float4 bb = x4[(size_t)2 * d + 1];
                    float* p = agg_extra + (size_t)s * 8;
                    atomicAdd(p + 0, a.x); atomicAdd(p + 1, a.y);
                    atomicAdd(p + 2, a.z); atomicAdd(p + 3, a.w);
                    atomicAdd(p + 4, bb.x); atomicAdd(p + 5, bb.y);
                    atomicAdd(p + 6, bb.z); atomicAdd(p + 7, bb.w);
                    atomicAdd(deg_extra + s, 1.0f);
                }
            }
        } else {
            for (int j = 0; j < 4; ++j) {
                if (e + j >= N_EDGES) break;
                int s = ei[e + j], d = ei[N_EDGES + e + j];
                int b = s >> BSH;
                int pos = atomicAdd(&cntA[b], 1);
                int slot = baseB[b] + pos;
                if (slot < CAPB) {
                    region[(size_t)b * CAPB + slot] =
                        ((unsigned)(s & (BNODES - 1)) << 19) | (unsigned)d;
                } else {
                    float4 a = x4[(size_t)2 * d];
                    float4 bb = x4[(size_t)2 * d + 1];
                    float* p = agg_extra + (size_t)s * 8;
                    atomicAdd(p + 0, a.x); atomicAdd(p + 1, a.y);
                    atomicAdd(p + 2, a.z); atomicAdd(p + 3, a.w);
                    atomicAdd(p + 4, bb.x); atomicAdd(p + 5, bb.y);
                    atomicAdd(p + 6, bb.z); atomicAdd(p + 7, bb.w);
                    atomicAdd(deg_extra + s, 1.0f);
                }
            }
        }
    }
}

// ---- phase 2: per-bucket counting sort + register accumulate --------------
__device__ __forceinline__ void addx(float* s, uint4 v) {
    const __half2* h = (const __half2*)&v;
    #pragma unroll
    for (int c = 0; c < 4; ++c) {
        float2 f = __half22float2(h[c]);
        s[2 * c]     += f.x;
        s[2 * c + 1] += f.y;
    }
}

__global__ __launch_bounds__(512) void k_gather(
    const unsigned* __restrict__ region, const int* __restrict__ gcnt,
    const uint4* __restrict__ xh,
    const float4* __restrict__ agg_extra4, const float* __restrict__ deg_extra,
    float4* __restrict__ agg4, float* __restrict__ degf)
{
    __shared__ unsigned sorted[CAPB];    // 36.9 KB
    __shared__ int cnt[BNODES];          // histogram (preserved)
    __shared__ int scan[BNODES];         // inclusive scan
    __shared__ int run[BNODES];          // scatter cursors
    int tid = threadIdx.x;
    int b = blockIdx.x;

    cnt[tid] = 0;
    run[tid] = 0;
    __syncthreads();

    int ne = gcnt[b];
    if (ne > CAPB) ne = CAPB;
    const unsigned* reg = region + (size_t)b * CAPB;

    // pass 1: histogram of local src (1 LDS atomic/edge)
    for (int i = tid; i < ne; i += 512)
        atomicAdd(&cnt[reg[i] >> 19], 1);
    __syncthreads();

    // inclusive Hillis-Steele scan over 512 counts
    scan[tid] = cnt[tid];
    __syncthreads();
    #pragma unroll
    for (int s = 1; s < BNODES; s <<= 1) {
        int v = (tid >= s) ? scan[tid - s] : 0;
        __syncthreads();
        scan[tid] += v;
        __syncthreads();
    }

    // pass 2: scatter dst ids to per-node contiguous runs (1 LDS atomic/edge)
    for (int i = tid; i < ne; i += 512) {
        unsigned p = reg[i];
        int ls = (int)(p >> 19);
        int pos = atomicAdd(&run[ls], 1);
        sorted[(scan[ls] - cnt[ls]) + pos] = p & DSTMASK;
    }
    __syncthreads();

    // pass 3: one thread per node, register accumulation (no atomics),
    // 8 independent gathers in flight
    int deg  = cnt[tid];
    int base = scan[tid] - cnt[tid];
    float s[8];
    #pragma unroll
    for (int c = 0; c < 8; ++c) s[c] = 0.0f;

    int j = 0;
    for (; j + 8 <= deg; j += 8) {
        uint4 xv[8];
        #pragma unroll
        for (int q = 0; q < 8; ++q) xv[q] = xh[sorted[base + j + q]];
        #pragma unroll
        for (int q = 0; q < 8; ++q) addx(s, xv[q]);
    }
    for (; j + 4 <= deg; j += 4) {
        uint4 x0 = xh[sorted[base + j]];
        uint4 x1 = xh[sorted[base + j + 1]];
        uint4 x2 = xh[sorted[base + j + 2]];
        uint4 x3 = xh[sorted[base + j + 3]];
        addx(s, x0); addx(s, x1); addx(s, x2); addx(s, x3);
    }
    for (; j < deg; ++j) {
        uint4 xv = xh[sorted[base + j]];
        addx(s, xv);
    }

    int gn = b * BNODES + tid;
    if (gn < N_NODES) {
        float4 e0 = agg_extra4[(size_t)2 * gn];
        float4 e1 = agg_extra4[(size_t)2 * gn + 1];
        agg4[(size_t)2 * gn] = make_float4(
            s[0] + e0.x, s[1] + e0.y, s[2] + e0.z, s[3] + e0.w);
        agg4[(size_t)2 * gn + 1] = make_float4(
            s[4] + e1.x, s[5] + e1.y, s[6] + e1.z, s[7] + e1.w);
        degf[gn] = (float)deg + deg_extra[gn];
    }
}

// ---- pack W into MFMA B-fragment order, split bf16 hi/lo ------------------
// Layout: P[(ks*8+ct)*2 + hl][lane 0..63][j 0..7]  (ushort)
__global__ __launch_bounds__(256) void k_pack(
    const float* __restrict__ W1, const float* __restrict__ W2,
    const float* __restrict__ W3,
    ushort* __restrict__ P1, ushort* __restrict__ P2, ushort* __restrict__ P3)
{
    int b = blockIdx.x;
    const float* W = (b == 0) ? W1 : ((b == 1) ? W2 : W3);
    ushort* P = (b == 0) ? P1 : ((b == 1) ? P2 : P3);
    int KS = (b == 0) ? 1 : 4;
    int total = KS * 8 * 64 * 8;
    for (int i = threadIdx.x; i < total; i += 256) {
        int j    = i & 7;
        int lane = (i >> 3) & 63;
        int ct   = (i >> 9) & 7;
        int ks   = i >> 12;
        int k = ks * 32 + (lane >> 4) * 8 + j;
        int c = ct * 16 + (lane & 15);
        float wv = 0.0f;
        if (b == 0) { if (k < 8) wv = W[k * HID + c]; }
        else        { wv = W[k * HID + c]; }
        ushort hi = f2bf(wv);
        float  lo = wv - bf2f(hi);
        P[(((ks * 8 + ct) * 2 + 0) * 64 + lane) * 8 + j] = hi;
        P[(((ks * 8 + ct) * 2 + 1) * 64 + lane) * 8 + j] = f2bf(lo);
    }
}

// ---- one MFMA layer, 32 rows/wave, W fragments read from LDS --------------
// WL holds the layer's packed P (hi/lo interleaved, same layout as global).
// ds_read_b128 latency (~120cy) is compiler-covered via lgkmcnt(N)
// interleaving (m97 evidence) - unlike L2 loads, which it never pipelined.
template<int KS, bool STORE>
__device__ __forceinline__ void mfma_layer_lds(
    ushort (&H)[MNPB][HPAD], const ushort* WL, const float* __restrict__ bias,
    int rbase, int l, float* csum, int nbase)
{
    const int cl = l & 15;
    const int g  = l >> 4;

    f32x4 acc[8][2];
    #pragma unroll
    for (int ct = 0; ct < 8; ++ct) {
        float bv = bias[ct * 16 + cl];
        f32x4 b4 = {bv, bv, bv, bv};
        acc[ct][0] = b4;
        acc[ct][1] = b4;
    }

    #pragma unroll
    for (int ks = 0; ks < KS; ++ks) {
        bf16x8 A0, A1;
        {
            int col = ks * 32 + g * 8;
            A0 = *(const bf16x8*)&H[rbase + cl][col];
            A1 = *(const bf16x8*)&H[rbase + 16 + cl][col];
        }
        #pragma unroll
        for (int ct = 0; ct < 8; ++ct) {
            const ushort* pb = WL + ((ks * 8 + ct) * 1024 + l * 8);
            bf16x8 Bh = *(const bf16x8*)pb;
            bf16x8 Bl = *(const bf16x8*)(pb + 512);
            acc[ct][0] = __builtin_amdgcn_mfma_f32_16x16x32_bf16(A0, Bh, acc[ct][0], 0, 0, 0);
            acc[ct][1] = __builtin_amdgcn_mfma_f32_16x16x32_bf16(A1, Bh, acc[ct][1], 0, 0, 0);
            acc[ct][0] = __builtin_amdgcn_mfma_f32_16x16x32_bf16(A0, Bl, acc[ct][0], 0, 0, 0);
            acc[ct][1] = __builtin_amdgcn_mfma_f32_16x16x32_bf16(A1, Bl, acc[ct][1], 0, 0, 0);
        }
    }

    if (STORE) {
        #pragma unroll
        for (int ct = 0; ct < 8; ++ct) {
            #pragma unroll
            for (int rt = 0; rt < 2; ++rt) {
                f32x4 a = acc[ct][rt];
                unsigned p0 = cvt_pk_bf16(fmaxf(a[0], 0.f), fmaxf(a[1], 0.f));
                unsigned p1 = cvt_pk_bf16(fmaxf(a[2], 0.f), fmaxf(a[3], 0.f));
                int r0 = rbase + rt * 16 + g * 4;
                int c  = ct * 16 + cl;
                H[r0 + 0][c] = (ushort)p0;
                H[r0 + 1][c] = (ushort)(p0 >> 16);
                H[r0 + 2][c] = (ushort)p1;
                H[r0 + 3][c] = (ushort)(p1 >> 16);
            }
        }
    } else {
        #pragma unroll
        for (int ct = 0; ct < 8; ++ct) {
            float part = 0.0f;
            #pragma unroll
            for (int rt = 0; rt < 2; ++rt) {
                f32x4 a = acc[ct][rt];
                #pragma unroll
                for (int j = 0; j < 4; ++j) {
                    int gn = nbase + rbase + rt * 16 + g * 4 + j;
                    float h = fmaxf(a[j], 0.0f);
                    part += (gn < N_NODES) ? h : 0.0f;
                }
            }
            part += __shfl_xor(part, 16, 64);
            part += __shfl_xor(part, 32, 64);
            if (g == 0) atomicAdd(&csum[ct * 16 + cl], part);
        }
    }
}

// ---- fused 3-layer MLP: 8 waves x 32 rows, W staged in LDS per layer ------
__global__ __launch_bounds__(512, 2) void k_mlp_mfma(
    const float4* __restrict__ x4, const float4* __restrict__ agg4,
    const float* __restrict__ degf,
    const ushort* __restrict__ P1, const float* __restrict__ b1,
    const ushort* __restrict__ P2, const float* __restrict__ b2,
    const ushort* __restrict__ P3, const float* __restrict__ b3,
    float* __restrict__ colsum)
{
    __shared__ ushort H[MNPB][HPAD];     // 69.6 KB
    __shared__ ushort WL[32768];         // 64 KB layer-W buffer
    __shared__ float csum[HID];          // total ~135.7 KB -> 1 block/CU

    const int tid = threadIdx.x;        // 0..511
    const int wv  = tid >> 6;           // 0..7
    const int l   = tid & 63;
    const int rbase = wv * 32;          // wave owns rows [rbase, rbase+32)
    const int nbase = blockIdx.x * MNPB;

    if (tid < HID) csum[tid] = 0.0f;

    if (l < 32) {
        int rr = l;
        int gn = nbase + rbase + rr;
        float vv[8];
        if (gn < N_NODES) {
            float4 xa = x4[(size_t)2 * gn], xb = x4[(size_t)2 * gn + 1];
            float4 a0 = agg4[(size_t)2 * gn];
            float4 a1 = agg4[(size_t)2 * gn + 1];
            float rd = 1.0f / fmaxf(degf[gn], 1.0f);
            vv[0] = xa.x + a0.x * rd; vv[1] = xa.y + a0.y * rd;
            vv[2] = xa.z + a0.z * rd; vv[3] = xa.w + a0.w * rd;
            vv[4] = xb.x + a1.x * rd; vv[5] = xb.y + a1.y * rd;
            vv[6] = xb.z + a1.z * rd; vv[7] = xb.w + a1.w * rd;
        } else {
            #pragma unroll
            for (int j = 0; j < 8; ++j) vv[j] = 0.0f;
        }
        uint4 hv;
        hv.x = cvt_pk_bf16(vv[0], vv[1]);
        hv.y = cvt_pk_bf16(vv[2], vv[3]);
        hv.z = cvt_pk_bf16(vv[4], vv[5]);
        hv.w = cvt_pk_bf16(vv[6], vv[7]);
        int row = rbase + rr;
        uint4 z = {0, 0, 0, 0};
        *(uint4*)&H[row][0]  = hv;
        *(uint4*)&H[row][8]  = z;
        *(uint4*)&H[row][16] = z;
        *(uint4*)&H[row][24] = z;
    }

    uint4* WL4 = (uint4*)WL;

    // ---- layer 1: stage P1 (16 KB = 1024 uint4), compute
    for (int i = tid; i < 1024; i += 512) WL4[i] = ((const uint4*)P1)[i];
    __syncthreads();
    mfma_layer_lds<1, true >(H, WL, b1, rbase, l, csum, nbase);
    __syncthreads();

    // ---- layer 2: stage P2 (64 KB = 4096 uint4), compute
    for (int i = tid; i < 4096; i += 512) WL4[i] = ((const uint4*)P2)[i];
    __syncthreads();
    mfma_layer_lds<4, true >(H, WL, b2, rbase, l, csum, nbase);
    __syncthreads();

    // ---- layer 3: stage P3, compute + column reduce
    for (int i = tid; i < 4096; i += 512) WL4[i] = ((const uint4*)P3)[i];
    __syncthreads();
    mfma_layer_lds<4, false>(H, WL, b3, rbase, l, csum, nbase);

    __syncthreads();
    if (tid < HID) atomicAdd(&colsum[tid], csum[tid]);
}

// ---- fallback path kernels (ws too small) ---------------------------------
__global__ __launch_bounds__(256) void k_scatter(
    const int* __restrict__ ei, const float4* __restrict__ x4,
    float* __restrict__ agg, float* __restrict__ deg)
{
    int e = blockIdx.x * 256 + threadIdx.x;
    if (e >= N_EDGES) return;
    int s = ei[e];
    int d = ei[N_EDGES + e];
    atomicAdd(deg + s, 1.0f);
    float4 a = x4[(size_t)2 * d];
    float4 b = x4[(size_t)2 * d + 1];
    float* p = agg + (size_t)s * 8;
    atomicAdd(p + 0, a.x); atomicAdd(p + 1, a.y);
    atomicAdd(p + 2, a.z); atomicAdd(p + 3, a.w);
    atomicAdd(p + 4, b.x); atomicAdd(p + 5, b.y);
    atomicAdd(p + 6, b.z); atomicAdd(p + 7, b.w);
}

__device__ __forceinline__ void matvec128(
    const float (&Hin)[NPB][LDP],
    const float* __restrict__ W, const float* __restrict__ bias,
    int n0, int j0, float (&acc)[4][8])
{
    {
        float4 bb0 = *(const float4*)(bias + j0);
        float4 bb1 = *(const float4*)(bias + j0 + 4);
        #pragma unroll
        for (int r = 0; r < 4; ++r) {
            acc[r][0] = bb0.x; acc[r][1] = bb0.y; acc[r][2] = bb0.z; acc[r][3] = bb0.w;
            acc[r][4] = bb1.x; acc[r][5] = bb1.y; acc[r][6] = bb1.z; acc[r][7] = bb1.w;
        }
    }
    for (int k = 0; k < 128; k += 4) {
        float h[4][4];
        #pragma unroll
        for (int r = 0; r < 4; ++r) {
            float4 hv = *(const float4*)&Hin[n0 + r][k];
            h[r][0] = hv.x; h[r][1] = hv.y; h[r][2] = hv.z; h[r][3] = hv.w;
        }
        #pragma unroll
        for (int kk = 0; kk < 4; ++kk) {
            const float* wr = W + (size_t)(k + kk) * HID + j0;
            float4 w0 = *(const float4*)(wr);
            float4 w1 = *(const float4*)(wr + 4);
            float w[8] = {w0.x, w0.y, w0.z, w0.w, w1.x, w1.y, w1.z, w1.w};
            #pragma unroll
            for (int r = 0; r < 4; ++r) {
                float hv = h[r][kk];
                #pragma unroll
                for (int c = 0; c < 8; ++c)
                    acc[r][c] = fmaf(hv, w[c], acc[r][c]);
            }
        }
    }
}

__global__ __launch_bounds__(256, 4) void k_mlp(
    const float4* __restrict__ x4, const float4* __restrict__ agg4,
    const float* __restrict__ degf,
    const float* __restrict__ W1, const float* __restrict__ b1,
    const float* __restrict__ W2, const float* __restrict__ b2,
    const float* __restrict__ W3, const float* __restrict__ b3,
    float* __restrict__ colsum)
{
    __shared__ float A[NPB][LDP];
    __shared__ float csum[HID];

    int tid  = threadIdx.x;
    int cidx = tid & 15;
    int nidx = tid >> 4;
    int j0 = cidx * 8;
    int n0 = nidx * 4;
    int nbase = blockIdx.x * NPB;

    if (tid < HID) csum[tid] = 0.0f;

    float v[4][8];
    #pragma unroll
    for (int r = 0; r < 4; ++r) {
        int gn = nbase + n0 + r;
        if (gn < N_NODES) {
            float4 xa = x4[(size_t)2 * gn], xb = x4[(size_t)2 * gn + 1];
            float4 aa = agg4[(size_t)2 * gn], ab = agg4[(size_t)2 * gn + 1];
            float rd = 1.0f / fmaxf(degf[gn], 1.0f);
            v[r][0] = xa.x + aa.x * rd; v[r][1] = xa.y + aa.y * rd;
            v[r][2] = xa.z + aa.z * rd; v[r][3] = xa.w + aa.w * rd;
            v[r][4] = xb.x + ab.x * rd; v[r][5] = xb.y + ab.y * rd;
            v[r][6] = xb.z + ab.z * rd; v[r][7] = xb.w + ab.w * rd;
        } else {
            #pragma unroll
            for (int k = 0; k < 8; ++k) v[r][k] = 0.0f;
        }
    }

    float acc[4][8];
    {
        float4 bb0 = *(const float4*)(b1 + j0);
        float4 bb1 = *(const float4*)(b1 + j0 + 4);
        #pragma unroll
        for (int r = 0; r < 4; ++r) {
            acc[r][0] = bb0.x; acc[r][1] = bb0.y; acc[r][2] = bb0.z; acc[r][3] = bb0.w;
            acc[r][4] = bb1.x; acc[r][5] = bb1.y; acc[r][6] = bb1.z; acc[r][7] = bb1.w;
        }
    }
    #pragma unroll
    for (int k = 0; k < 8; ++k) {
        const float* wr = W1 + (size_t)k * HID + j0;
        float4 w0 = *(const float4*)(wr);
        float4 w1 = *(const float4*)(wr + 4);
        float w[8] = {w0.x, w0.y, w0.z, w0.w, w1.x, w1.y, w1.z, w1.w};
        #pragma unroll
        for (int r = 0; r < 4; ++r) {
            float hv = v[r][k];
            #pragma unroll
            for (int c = 0; c < 8; ++c) acc[r][c] = fmaf(hv, w[c], acc[r][c]);
        }
    }
    #pragma unroll
    for (int r = 0; r < 4; ++r) {
        *(float4*)&A[n0 + r][j0] = make_float4(
            fmaxf(acc[r][0], 0.f), fmaxf(acc[r][1], 0.f),
            fmaxf(acc[r][2], 0.f), fmaxf(acc[r][3], 0.f));
        *(float4*)&A[n0 + r][j0 + 4] = make_float4(
            fmaxf(acc[r][4], 0.f), fmaxf(acc[r][5], 0.f),
            fmaxf(acc[r][6], 0.f), fmaxf(acc[r][7], 0.f));
    }
    __syncthreads();

    matvec128(A, W2, b2, n0, j0, acc);
    __syncthreads();
    #pragma unroll
    for (int r = 0; r < 4; ++r) {
        *(float4*)&A[n0 + r][j0] = make_float4(
            fmaxf(acc[r][0], 0.f), fmaxf(acc[r][1], 0.f),
            fmaxf(acc[r][2], 0.f), fmaxf(acc[r][3], 0.f));
        *(float4*)&A[n0 + r][j0 + 4] = make_float4(
            fmaxf(acc[r][4], 0.f), fmaxf(acc[r][5], 0.f),
            fmaxf(acc[r][6], 0.f), fmaxf(acc[r][7], 0.f));
    }
    __syncthreads();

    matvec128(A, W3, b3, n0, j0, acc);

    float part[8];
    #pragma unroll
    for (int c = 0; c < 8; ++c) part[c] = 0.0f;
    #pragma unroll
    for (int r = 0; r < 4; ++r) {
        if (nbase + n0 + r < N_NODES) {
            #pragma unroll
            for (int c = 0; c < 8; ++c) part[c] += fmaxf(acc[r][c], 0.f);
        }
    }
    #pragma unroll
    for (int c = 0; c < 8; ++c) atomicAdd(&csum[j0 + c], part[c]);
    __syncthreads();
    if (tid < HID) atomicAdd(colsum + tid, csum[tid]);
}

__global__ void k_final(const float* __restrict__ colsum,
                        const float* __restrict__ Wv, const float* __restrict__ bv,
                        float* __restrict__ out)
{
    __shared__ float red[2];
    int t = threadIdx.x;  // 128 threads
    float vv = colsum[t] * (1.0f / (float)N_NODES) * Wv[t];
    #pragma unroll
    for (int m = 32; m >= 1; m >>= 1) vv += __shfl_xor(vv, m, 64);
    if ((t & 63) == 0) red[t >> 6] = vv;
    __syncthreads();
    if (t == 0) out[0] = tanhf(red[0] + red[1] + bv[0]);
}

extern "C" void kernel_launch(void* const* d_in, const int* in_sizes, int n_in,
                              void* d_out, int out_size, void* d_ws, size_t ws_size,
                              hipStream_t stream)
{
    const float* x  = (const float*)d_in[0];
    const int*   ei = (const int*)d_in[1];
    const float* W1 = (const float*)d_in[2];
    const float* b1 = (const float*)d_in[3];
    const float* W2 = (const float*)d_in[4];
    const float* b2 = (const float*)d_in[5];
    const float* W3 = (const float*)d_in[6];
    const float* b3 = (const float*)d_in[7];
    const float* Wv = (const float*)d_in[8];
    const float* bv = (const float*)d_in[9];
    float* out = (float*)d_out;

    char* ws = (char*)d_ws;
    const size_t OFF_GCNT   = 0;
    const size_t OFF_COLSUM = 4096;
    const size_t OFF_DEGX   = 4608;
    const size_t OFF_AGGX   = 2004608;
    const size_t OFF_REGION = 18004608;
    const size_t OFF_AGG    = 54020736;
    const size_t OFF_DEGF   = 70020736;
    const size_t OFF_XH     = 72020736;
    const size_t OFF_PACK1  = 80020736;
    const size_t OFF_PACK2  = 80037120;
    const size_t OFF_PACK3  = 80102656;
    const size_t WS_NEED    = 80168192;

    if (ws_size >= WS_NEED) {
        int*      gcnt   = (int*)(ws + OFF_GCNT);
        float*    colsum = (float*)(ws + OFF_COLSUM);
        float*    degx   = (float*)(ws + OFF_DEGX);
        float*    aggx   = (float*)(ws + OFF_AGGX);
        unsigned* region = (unsigned*)(ws + OFF_REGION);
        float*    agg    = (float*)(ws + OFF_AGG);
        float*    degf   = (float*)(ws + OFF_DEGF);
        uint4*    xh     = (uint4*)(ws + OFF_XH);
        ushort*   P1     = (ushort*)(ws + OFF_PACK1);
        ushort*   P2     = (ushort*)(ws + OFF_PACK2);
        ushort*   P3     = (ushort*)(ws + OFF_PACK3);

        hipMemsetAsync(ws, 0, OFF_REGION, stream);  // gcnt+colsum+extras

        k_xhalf<<<(N_NODES + 255) / 256, 256, 0, stream>>>((const float4*)x, xh);

        k_pack<<<3, 256, 0, stream>>>(W1, W2, W3, P1, P2, P3);

        k_bin<<<(N_EDGES + EPB - 1) / EPB, 256, 0, stream>>>(
            ei, (const float4*)x, gcnt, region, aggx, degx);

        k_gather<<<NBUCK, 512, 0, stream>>>(
            region, gcnt, xh,
            (const float4*)aggx, degx, (float4*)agg, degf);

        k_mlp_mfma<<<(N_NODES + MNPB - 1) / MNPB, 512, 0, stream>>>(
            (const float4*)x, (const float4*)agg, degf,
            P1, b1, P2, b2, P3, b3, colsum);

        k_final<<<1, 128, 0, stream>>>(colsum, Wv, bv, out);
    } else {
        float* agg    = (float*)(ws);
        float* deg    = (float*)(ws + (size_t)N_NODES * 8 * 4);
        float* colsum = (float*)(ws + (size_t)N_NODES * 8 * 4 + (size_t)N_NODES * 4);
        size_t zero_bytes = (size_t)N_NODES * 8 * 4 + (size_t)N_NODES * 4 + HID * 4;

        hipMemsetAsync(d_ws, 0, zero_bytes, stream);

        k_scatter<<<(N_EDGES + 255) / 256, 256, 0, stream>>>(
            ei, (const float4*)x, agg, deg);

        k_mlp<<<(N_NODES + NPB - 1) / NPB, 256, 0, stream>>>(
            (const float4*)x, (const float4*)agg, deg,
            W1, b1, W2, b2, W3, b3, colsum);

        k_final<<<1, 128, 0, stream>>>(colsum, Wv, bv, out);
    }
}